// Round 2
// baseline (161.330 us; speedup 1.0000x reference)
//
#include <hip/hip_runtime.h>
#include <hip/hip_bf16.h>

// Joint network: out[b,t,u,o] = tanh(enc_proj[b,t,:] + dec_proj[b,u,:] + b1) @ W2 + b2
// B=8 T=256 U=64 D=512 H=1024 O=128.  All I/O fp32.
//
// tanh identity: with C2L = 2*log2(e),
//   tanh(x) = 1 - 2/(2^(C2L*x) + 1),  2^(C2L*(e+d+b1)) = Ep * Dp
// Ep/Dp precomputed fp16 in the projection epilogue. In the hot loop:
//   p = min(Ep*Dp + 1, 126)            (cap: err <= 0.016 where tanh ~ 1)
//   pairwise: rq = rcph(p0*p1); 1/p0 = p1*rq; 1/p1 = p0*rq   (4 rcph per 8)
//   A = 1 - 2*r
//
// ws: W1T f16 [1024][1024] @0 (2MiB) | W2T f16 [128][1024] @2MiB (256KiB)
//     Ep f16 [2048][1024] @2.25MiB (4MiB) | Dp f16 [512][1024] @6.25MiB (1MiB)

typedef _Float16 f16x8 __attribute__((ext_vector_type(8)));
typedef _Float16 f16x2 __attribute__((ext_vector_type(2)));
typedef float    f32x4 __attribute__((ext_vector_type(4)));

#define C2L 2.8853900817779268f

__device__ __forceinline__ float fast_exp2(float x) { return __builtin_amdgcn_exp2f(x); }

// v_cvt_pkrtz_f16_f32 returns __fp16x2 — bitcast to our _Float16x2
__device__ __forceinline__ f16x2 pk_cvt(float x, float y) {
    auto r = __builtin_amdgcn_cvt_pkrtz(x, y);
    union { decltype(r) a; f16x2 b; } c; c.a = r; return c.b;
}

// tanh on 8 packed f16 via pairwise reciprocal (4 rcph instead of 8).
// p = e*d + 1 in (1, inf); capped at 126 so q = p0*p1 <= 15876 keeps
// rq = rcph(q) >= 6.3e-5 in the f16 normal range (no denormal/overflow path).
__device__ __forceinline__ f16x8 tanh8(f16x8 e, f16x8 d) {
    const f16x8 one = {1,1,1,1,1,1,1,1};
    const f16x8 two = {2,2,2,2,2,2,2,2};
    const f16x8 cap = {126,126,126,126,126,126,126,126};
    union { f16x8 v; _Float16 s[8]; } p, r;
    p.v = e * d + one;                              // v_pk_fma_f16 x4
    p.v = __builtin_elementwise_min(p.v, cap);      // v_pk_min_f16 x4
    #pragma unroll
    for (int i = 0; i < 4; ++i) {
        _Float16 q  = p.s[2*i] * p.s[2*i+1];
        _Float16 rq = __builtin_amdgcn_rcph(q);
        r.s[2*i]   = p.s[2*i+1] * rq;               // = 1/p0
        r.s[2*i+1] = p.s[2*i]   * rq;               // = 1/p1
    }
    return one - two * r.v;                         // v_pk_fma_f16 x4
}

// async 16B global -> LDS (LDS dest is wave-uniform base + lane*16)
__device__ __forceinline__ void stage16(const void* g, void* l) {
    __builtin_amdgcn_global_load_lds(
        (const __attribute__((address_space(1))) unsigned int*)g,
        (__attribute__((address_space(3))) unsigned int*)l, 16, 0, 0);
}

// ---------------------------------------------------------------- transpose
// 64x64 f32 tiles via LDS; float4 global loads, f16x8 (16B) global stores.
// (Old version stored 2B per lane -> 64B per wave-store; W1T = 2MiB of those.)
// bi < 256: W1 (1024x1024) -> W1T ; bi >= 256: W2 (1024x128) -> W2T
__global__ __launch_bounds__(256) void transpose_both(
    const float* __restrict__ W1, const float* __restrict__ W2,
    _Float16* __restrict__ W1T, _Float16* __restrict__ W2T)
{
    __shared__ float tile[64][65];
    int bi = blockIdx.x;
    const float* src; _Float16* dst; int C, r0, c0;
    if (bi < 256) { src = W1; dst = W1T; C = 1024; r0 = (bi >> 4) << 6; c0 = (bi & 15) << 6; }
    else { int b2i = bi - 256; src = W2; dst = W2T; C = 128; r0 = (b2i >> 1) << 6; c0 = (b2i & 1) << 6; }
    int t = threadIdx.x;
    #pragma unroll
    for (int i = 0; i < 4; ++i) {
        int c = i * 256 + t;                 // 0..1023: 64 rows x 16 float4
        int row = c >> 4, c4 = (c & 15) << 2;
        *reinterpret_cast<float4*>(&tile[row][c4]) =
            *reinterpret_cast<const float4*>(src + (size_t)(r0 + row) * C + c0 + c4);
    }
    __syncthreads();
    #pragma unroll
    for (int i = 0; i < 2; ++i) {
        int d = i * 256 + t;                 // 0..511: 64 cols x 8 chunks
        int cc = d >> 3, rj = (d & 7) << 3;
        f16x8 v;
        #pragma unroll
        for (int e = 0; e < 8; ++e) v[e] = (_Float16)tile[rj + e][cc];
        *reinterpret_cast<f16x8*>(dst + (size_t)(c0 + cc) * 1024 + r0 + rj) = v;
    }
}

// ---------------------------------------------------------------- projections
// rows 0..2047 -> Ep = 2^(C2L*(enc@W1[:512] + b1)); rows 2048.. -> Dp (dec, no bias)
__global__ __launch_bounds__(256) void proj_exp(
    const float* __restrict__ enc,     // [2048][512]
    const float* __restrict__ dec,     // [512][512]
    const _Float16* __restrict__ W1T,  // [1024][1024]
    const float* __restrict__ b1,      // [1024]
    _Float16* __restrict__ Ep,         // [2048][1024]
    _Float16* __restrict__ Dp)         // [512][1024]
{
    const int K = 512;
    int tid  = threadIdx.x;
    int w    = tid >> 6, lane = tid & 63;
    int quad = lane >> 4, l15 = lane & 15;
    int m_base = blockIdx.y * 64 + w * 16;
    int n_base = blockIdx.x * 64;

    bool is_enc = (m_base < 2048);
    const float* A = is_enc ? (enc + (size_t)(m_base + l15) * K)
                            : (dec + (size_t)(m_base - 2048 + l15) * K);
    int koff = is_enc ? 0 : 512;

    f32x4 acc[4] = {};
    for (int kc = 0; kc < K; kc += 32) {
        int k = kc + quad * 8;
        float4 a_lo = *reinterpret_cast<const float4*>(A + k);
        float4 a_hi = *reinterpret_cast<const float4*>(A + k + 4);
        union { f16x8 v; f16x2 h[4]; } a;
        a.h[0] = pk_cvt(a_lo.x, a_lo.y);
        a.h[1] = pk_cvt(a_lo.z, a_lo.w);
        a.h[2] = pk_cvt(a_hi.x, a_hi.y);
        a.h[3] = pk_cvt(a_hi.z, a_hi.w);
        #pragma unroll
        for (int f = 0; f < 4; ++f) {
            int n = n_base + f * 16 + l15;
            f16x8 b = *reinterpret_cast<const f16x8*>(W1T + n * 1024 + koff + k);
            acc[f] = __builtin_amdgcn_mfma_f32_16x16x32_f16(a.v, b, acc[f], 0, 0, 0);
        }
    }

    #pragma unroll
    for (int f = 0; f < 4; ++f) {
        int col = n_base + f * 16 + l15;
        float bv = is_enc ? b1[col] : 0.0f;
        #pragma unroll
        for (int v = 0; v < 4; ++v) {
            int row = m_base + quad * 4 + v;
            float val = fast_exp2(C2L * (acc[f][v] + bv));
            if (is_enc) Ep[(size_t)row * 1024 + col] = (_Float16)val;
            else        Dp[(size_t)(row - 2048) * 1024 + col] = (_Float16)val;
        }
    }
}

// ---------------------------------------------------------------- main fused
// Block = (b, t-quad): 4 t x 64 u x 128 o. 4 waves; wave w owns u-rows
// [16w,16w+16) for all 4 t. Latency-bound regime (R1 counters: matrix 32%,
// LDS 25%, VALU 14%, HBM 18% — all idle 60%), so this round removes the
// per-tile global d8 load (Dp k-tile staged to LDS via the same proven XOR
// pattern as W2T; 0-conflict read structure identical to bb), staggers the
// k-tile start phase of co-resident blocks (breaks barrier phase-locking;
// fp32 accumulation reorder only), and wraps MFMA clusters in setprio(1)
// (T5: helps when co-resident waves are independently phased).
// LDS: 2x(16K W2T + 8K Dp) + 8K Ep = 56 KiB. Regs unchanged (~252/wave,
// 2 blocks/CU).
__global__ __launch_bounds__(256, 2) void joint_main(
    const _Float16* __restrict__ Ep,   // [2048][1024]
    const _Float16* __restrict__ Dp,   // [512][1024]
    const _Float16* __restrict__ W2T,  // [128][1024]
    const float* __restrict__ b2,      // [128]
    float* __restrict__ out)           // [8][256][64][128]
{
    __shared__ _Float16 sW[2][128 * 64];   // 2 x 16 KiB
    __shared__ _Float16 sD[2][64 * 64];    // 2 x 8 KiB
    __shared__ _Float16 sE[4 * 1024];      // 8 KiB: 4 Ep rows

    int t0 = blockIdx.x * 4, b = blockIdx.y;
    int tid  = threadIdx.x;
    int w    = tid >> 6, lane = tid & 63;
    int quad = lane >> 4, l15 = lane & 15;
    int u0   = w * 16;
    // co-resident blocks are typically dispatch d and d+256 (= blockIdx.y+4):
    // give them opposite k-tile phases so barrier cadences interleave.
    int rot  = ((blockIdx.y >> 2) & 1) << 3;

    const _Float16* epB = Ep + (size_t)(b * 256 + t0) * 1024;   // 4 contiguous rows
    const _Float16* dpB = Dp + (size_t)(b * 64) * 1024;

    f32x4 acc[4][8] = {};   // [t][o-tile] = 128 AGPRs

    // stage 4 Ep rows (8 KiB, linear both sides): 512 chunks, 2 per thread
    #pragma unroll
    for (int i = 0; i < 2; ++i) {
        int c = i * 256 + tid;
        stage16(epB + c * 8, sE + (i * 256 + (tid & 0xC0)) * 8);
    }
    // stage k-tile 'rot' into buf 0: W2T 1024 chunks (4/thread), Dp 512 (2/thread)
    {
        int kb = rot * 64;
        #pragma unroll
        for (int i = 0; i < 4; ++i) {
            int c = i * 256 + tid;
            int row = c >> 3, kcs = c & 7;
            stage16(W2T + row * 1024 + kb + ((kcs ^ (row & 7)) << 3),
                    &sW[0][(i * 256 + (tid & 0xC0)) * 8]);
        }
        #pragma unroll
        for (int i = 0; i < 2; ++i) {
            int c = i * 256 + tid;
            int row = c >> 3, kcs = c & 7;
            stage16(dpB + row * 1024 + kb + ((kcs ^ (row & 7)) << 3),
                    &sD[0][(i * 256 + (tid & 0xC0)) * 8]);
        }
    }

    int rowu = u0 + l15;
    int rx   = rowu & 7;

    for (int ii = 0; ii < 16; ++ii) {
        int it = (ii + rot) & 15;
        __syncthreads();   // drains stage(ii) — issued one full tile ago (and sE at ii=0)
        if (ii < 15) {
            int kb = (((ii + 1) + rot) & 15) * 64;
            _Float16* dw = sW[(ii + 1) & 1];
            _Float16* dd = sD[(ii + 1) & 1];
            #pragma unroll
            for (int i = 0; i < 4; ++i) {
                int c = i * 256 + tid;
                int row = c >> 3, kcs = c & 7;
                stage16(W2T + row * 1024 + kb + ((kcs ^ (row & 7)) << 3),
                        dw + (i * 256 + (tid & 0xC0)) * 8);
            }
            #pragma unroll
            for (int i = 0; i < 2; ++i) {
                int c = i * 256 + tid;
                int row = c >> 3, kcs = c & 7;
                stage16(dpB + row * 1024 + kb + ((kcs ^ (row & 7)) << 3),
                        dd + (i * 256 + (tid & 0xC0)) * 8);
            }
        }
        const _Float16* sw = sW[ii & 1];
        const _Float16* sd = sD[ii & 1];
        #pragma unroll
        for (int ki2 = 0; ki2 < 2; ++ki2) {
            int kc3 = ki2 * 4 + quad;
            // d8 from LDS (swizzled slot; same 16-row/xor structure as bb -> 0-conflict)
            f16x8 d8 = *reinterpret_cast<const f16x8*>(sd + rowu * 64 + ((kc3 ^ rx) << 3));
            int kq = it * 64 + ki2 * 32 + quad * 8;
            f16x8 A[4];
            #pragma unroll
            for (int tt = 0; tt < 4; ++tt) {
                // broadcast ds_read_b128 (same addr per quad group): conflict-free
                f16x8 e = *reinterpret_cast<const f16x8*>(sE + tt * 1024 + kq);
                A[tt] = tanh8(e, d8);
            }
            int swo = (kc3 ^ (l15 & 7)) << 3;        // uniform across f
            __builtin_amdgcn_s_setprio(1);
            #pragma unroll
            for (int f = 0; f < 8; ++f) {
                f16x8 bb = *reinterpret_cast<const f16x8*>(
                    sw + (f * 16 + l15) * 64 + swo);
                #pragma unroll
                for (int tt = 0; tt < 4; ++tt)
                    acc[tt][f] = __builtin_amdgcn_mfma_f32_16x16x32_f16(A[tt], bb, acc[tt][f], 0, 0, 0);
            }
            __builtin_amdgcn_s_setprio(0);
        }
    }

    #pragma unroll
    for (int tt = 0; tt < 4; ++tt) {
        float* o = out + (size_t)(b * 256 + t0 + tt) * 64 * 128;
        #pragma unroll
        for (int f = 0; f < 8; ++f) {
            int oc = f * 16 + l15;
            float bv = b2[oc];
            #pragma unroll
            for (int v = 0; v < 4; ++v) {
                int u = u0 + quad * 4 + v;
                o[u * 128 + oc] = acc[tt][f][v] + bv;
            }
        }
    }
}

// ---------------------------------------------------------------- launch
extern "C" void kernel_launch(void* const* d_in, const int* in_sizes, int n_in,
                              void* d_out, int out_size, void* d_ws, size_t ws_size,
                              hipStream_t stream) {
    const float* enc = (const float*)d_in[0]; // [8][256][512]
    const float* dec = (const float*)d_in[1]; // [8][64][512]
    const float* W1  = (const float*)d_in[2]; // [1024][1024]
    const float* b1  = (const float*)d_in[3]; // [1024]
    const float* W2  = (const float*)d_in[4]; // [1024][128]
    const float* b2  = (const float*)d_in[5]; // [128]
    float* out = (float*)d_out;

    char* ws = (char*)d_ws;
    _Float16* W1T = (_Float16*)(ws);                               // 2 MiB
    _Float16* W2T = (_Float16*)(ws + (2u << 20));                  // 256 KiB
    _Float16* EpP = (_Float16*)(ws + (2u << 20) + (256u << 10));   // 4 MiB
    _Float16* DpP = (_Float16*)(ws + (6u << 20) + (256u << 10));   // 1 MiB

    transpose_both<<<dim3(288), dim3(256), 0, stream>>>(W1, W2, W1T, W2T);

    // fused projections + exp2 epilogue: M = 2048 (enc) + 512 (dec)
    proj_exp<<<dim3(16, 40), 256, 0, stream>>>(enc, dec, W1T, b1, EpP, DpP);

    joint_main<<<dim3(64, 8), 256, 0, stream>>>(EpP, DpP, W2T, b2, out);
}

// Round 3
// 158.897 us; speedup vs baseline: 1.0153x; 1.0153x over previous
//
#include <hip/hip_runtime.h>
#include <hip/hip_bf16.h>

// Joint network: out[b,t,u,o] = tanh(enc_proj[b,t,:] + dec_proj[b,u,:] + b1) @ W2 + b2
// B=8 T=256 U=64 D=512 H=1024 O=128.  All I/O fp32.
//
// tanh identity: with C2L = 2*log2(e),
//   tanh(x) = 1 - 2/(2^(C2L*x) + 1),  2^(C2L*(e+d+b1)) = Ep * Dp
// Ep/Dp precomputed fp16 in the projection epilogue. In the hot loop:
//   p = min(Ep*Dp + 1, 126)            (cap: err <= 0.016 where tanh ~ 1)
//   pairwise: rq = rcph(p0*p1); 1/p0 = p1*rq; 1/p1 = p0*rq   (4 rcph per 8)
//   A = 1 - 2*r
//
// ws: W1T f16 [1024][1024] @0 (2MiB) | W2T f16 [128][1024] @2MiB (256KiB)
//     Ep f16 [2048][1024] @2.25MiB (4MiB) | Dp f16 [512][1024] @6.25MiB (1MiB)

typedef _Float16 f16x8 __attribute__((ext_vector_type(8)));
typedef _Float16 f16x2 __attribute__((ext_vector_type(2)));
typedef float    f32x4 __attribute__((ext_vector_type(4)));

#define C2L 2.8853900817779268f

__device__ __forceinline__ float fast_exp2(float x) { return __builtin_amdgcn_exp2f(x); }

// v_cvt_pkrtz_f16_f32 returns __fp16x2 — bitcast to our _Float16x2
__device__ __forceinline__ f16x2 pk_cvt(float x, float y) {
    auto r = __builtin_amdgcn_cvt_pkrtz(x, y);
    union { decltype(r) a; f16x2 b; } c; c.a = r; return c.b;
}

// tanh on 8 packed f16 via pairwise reciprocal (4 rcph instead of 8).
// p = e*d + 1 in (1, inf); capped at 126 so q = p0*p1 <= 15876 keeps
// rq = rcph(q) >= 6.3e-5 in the f16 normal range (no denormal/overflow path).
__device__ __forceinline__ f16x8 tanh8(f16x8 e, f16x8 d) {
    const f16x8 one = {1,1,1,1,1,1,1,1};
    const f16x8 two = {2,2,2,2,2,2,2,2};
    const f16x8 cap = {126,126,126,126,126,126,126,126};
    union { f16x8 v; _Float16 s[8]; } p, r;
    p.v = e * d + one;                              // v_pk_fma_f16 x4
    p.v = __builtin_elementwise_min(p.v, cap);      // v_pk_min_f16 x4
    #pragma unroll
    for (int i = 0; i < 4; ++i) {
        _Float16 q  = p.s[2*i] * p.s[2*i+1];
        _Float16 rq = __builtin_amdgcn_rcph(q);
        r.s[2*i]   = p.s[2*i+1] * rq;               // = 1/p0
        r.s[2*i+1] = p.s[2*i]   * rq;               // = 1/p1
    }
    return one - two * r.v;                         // v_pk_fma_f16 x4
}

// async 16B global -> LDS (LDS dest is wave-uniform base + lane*16)
__device__ __forceinline__ void stage16(const void* g, void* l) {
    __builtin_amdgcn_global_load_lds(
        (const __attribute__((address_space(1))) unsigned int*)g,
        (__attribute__((address_space(3))) unsigned int*)l, 16, 0, 0);
}

// ---------------------------------------------------------------- transpose
// bx<32: W1 (1024x1024) -> W1T ; bx>=32: W2 (1024x128) -> W2T
// (R0 version — the 64x64/f16x8-store rewrite measured slightly worse.)
__global__ __launch_bounds__(1024) void transpose_both(
    const float* __restrict__ W1, const float* __restrict__ W2,
    _Float16* __restrict__ W1T, _Float16* __restrict__ W2T)
{
    __shared__ float tile[32][33];
    int bx = blockIdx.x;
    const float* src; _Float16* dst; int C, c0;
    if (bx < 32) { src = W1; dst = W1T; C = 1024; c0 = bx * 32; }
    else         { src = W2; dst = W2T; C = 128;  c0 = (bx - 32) * 32; }
    int r0 = blockIdx.y * 32;
    int tx = threadIdx.x, ty = threadIdx.y;
    tile[ty][tx] = src[(r0 + ty) * C + (c0 + tx)];
    __syncthreads();
    dst[(size_t)(c0 + ty) * 1024 + (r0 + tx)] = (_Float16)tile[tx][ty];
}

// ---------------------------------------------------------------- projections
// rows 0..2047 -> Ep = 2^(C2L*(enc@W1[:512] + b1)); rows 2048.. -> Dp (dec, no bias)
// v2: per-wave tile 16x32 (was 16x64) -> 1280 blocks = 5 waves/SIMD (was 2.5);
// fully-unrolled K with one-iteration A-prefetch. proj was latency-bound at
// 2.5 waves/SIMD with cold HBM A-loads + L2 B-loads directly on the MFMA
// chain; TLP x2 + prefetch is the fix (VGPR ~60, occupancy stays grid-limited).
__global__ __launch_bounds__(256) void proj_exp(
    const float* __restrict__ enc,     // [2048][512]
    const float* __restrict__ dec,     // [512][512]
    const _Float16* __restrict__ W1T,  // [1024][1024]
    const float* __restrict__ b1,      // [1024]
    _Float16* __restrict__ Ep,         // [2048][1024]
    _Float16* __restrict__ Dp)         // [512][1024]
{
    const int K = 512;
    int tid  = threadIdx.x;
    int w    = tid >> 6, lane = tid & 63;
    int quad = lane >> 4, l15 = lane & 15;
    int m_base = blockIdx.y * 64 + w * 16;
    int n_base = blockIdx.x * 32;

    bool is_enc = (m_base < 2048);
    const float* A = is_enc ? (enc + (size_t)(m_base + l15) * K)
                            : (dec + (size_t)(m_base - 2048 + l15) * K);
    const _Float16* Bp = W1T + (is_enc ? 0 : 512);
    const _Float16* B0 = Bp + (size_t)(n_base + l15) * 1024;
    const _Float16* B1 = Bp + (size_t)(n_base + 16 + l15) * 1024;

    f32x4 acc[2] = {};
    float4 a_lo = *reinterpret_cast<const float4*>(A + quad * 8);
    float4 a_hi = *reinterpret_cast<const float4*>(A + quad * 8 + 4);
    #pragma unroll
    for (int kc = 0; kc < K; kc += 32) {
        int k = kc + quad * 8;
        f16x8 b0 = *reinterpret_cast<const f16x8*>(B0 + k);
        f16x8 b1v = *reinterpret_cast<const f16x8*>(B1 + k);
        float4 n_lo, n_hi;
        if (kc + 32 < K) {
            n_lo = *reinterpret_cast<const float4*>(A + k + 32);
            n_hi = *reinterpret_cast<const float4*>(A + k + 36);
        }
        union { f16x8 v; f16x2 h[4]; } a;
        a.h[0] = pk_cvt(a_lo.x, a_lo.y);
        a.h[1] = pk_cvt(a_lo.z, a_lo.w);
        a.h[2] = pk_cvt(a_hi.x, a_hi.y);
        a.h[3] = pk_cvt(a_hi.z, a_hi.w);
        acc[0] = __builtin_amdgcn_mfma_f32_16x16x32_f16(a.v, b0, acc[0], 0, 0, 0);
        acc[1] = __builtin_amdgcn_mfma_f32_16x16x32_f16(a.v, b1v, acc[1], 0, 0, 0);
        a_lo = n_lo; a_hi = n_hi;
    }

    #pragma unroll
    for (int f = 0; f < 2; ++f) {
        int col = n_base + f * 16 + l15;
        float bv = is_enc ? b1[col] : 0.0f;
        #pragma unroll
        for (int v = 0; v < 4; ++v) {
            int row = m_base + quad * 4 + v;
            float val = fast_exp2(C2L * (acc[f][v] + bv));
            if (is_enc) Ep[(size_t)row * 1024 + col] = (_Float16)val;
            else        Dp[(size_t)(row - 2048) * 1024 + col] = (_Float16)val;
        }
    }
}

// ---------------------------------------------------------------- main fused
// Block = (b, t-quad): 4 t x 64 u x 128 o. 4 waves; wave w owns u-rows
// [16w,16w+16) for all 4 t. Each W2T LDS fragment feeds 4 MFMAs.
// Ep rows (4 x 2 KiB) staged to LDS at block start; Dp stays as direct
// global loads (L2-resident, 128-way reused — staging it regressed, R2).
// W2T staged double-buffered (BK=64), one barrier per tile; XOR chunk
// swizzle keeps reads at 2-way bank aliasing with the lane-linear LDS dest
// required by global_load_lds.  (Exact R1 structure: best measured, 50.8 us.)
__global__ __launch_bounds__(256, 2) void joint_main(
    const _Float16* __restrict__ Ep,   // [2048][1024]
    const _Float16* __restrict__ Dp,   // [512][1024]
    const _Float16* __restrict__ W2T,  // [128][1024]
    const float* __restrict__ b2,      // [128]
    float* __restrict__ out)           // [8][256][64][128]
{
    __shared__ _Float16 sB[2][128 * 64];   // 2 x 16 KiB
    __shared__ _Float16 sE[4 * 1024];      // 8 KiB: 4 Ep rows

    int t0 = blockIdx.x * 4, b = blockIdx.y;
    int tid  = threadIdx.x;
    int w    = tid >> 6, lane = tid & 63;
    int quad = lane >> 4, l15 = lane & 15;
    int u0   = w * 16;

    const _Float16* epB = Ep + (size_t)(b * 256 + t0) * 1024;   // 4 contiguous rows
    const _Float16* dpr = Dp + (size_t)(b * 64 + u0 + l15) * 1024;

    f32x4 acc[4][8] = {};   // [t][o-tile] = 128 AGPRs

    // stage 4 Ep rows (8 KiB, linear both sides): 512 chunks, 2 per thread
    #pragma unroll
    for (int i = 0; i < 2; ++i) {
        int c = i * 256 + tid;
        stage16(epB + c * 8, sE + (i * 256 + (tid & 0xC0)) * 8);
    }
    // stage W2T tile 0 into buf 0 (1024 chunks of 16B, 4 per thread)
    #pragma unroll
    for (int i = 0; i < 4; ++i) {
        int c = i * 256 + tid;
        int row = c >> 3, kcs = c & 7;
        stage16(W2T + row * 1024 + ((kcs ^ (row & 7)) << 3),
                &sB[0][(i * 256 + (tid & 0xC0)) * 8]);
    }

    for (int it = 0; it < 16; ++it) {
        __syncthreads();   // drains stage(it) — issued one full tile ago (and sE at it=0)
        if (it < 15) {
            int kb = (it + 1) * 64;
            _Float16* dst = sB[(it + 1) & 1];
            #pragma unroll
            for (int i = 0; i < 4; ++i) {
                int c = i * 256 + tid;
                int row = c >> 3, kcs = c & 7;
                stage16(W2T + row * 1024 + kb + ((kcs ^ (row & 7)) << 3),
                        dst + (i * 256 + (tid & 0xC0)) * 8);
            }
        }
        const _Float16* sb = sB[it & 1];
        #pragma unroll
        for (int ki2 = 0; ki2 < 2; ++ki2) {
            int k = it * 64 + ki2 * 32 + quad * 8;
            f16x8 d8 = *reinterpret_cast<const f16x8*>(dpr + k);
            f16x8 A[4];
            #pragma unroll
            for (int tt = 0; tt < 4; ++tt) {
                // broadcast ds_read_b128 (same addr per quad group): conflict-free
                f16x8 e = *reinterpret_cast<const f16x8*>(sE + tt * 1024 + k);
                A[tt] = tanh8(e, d8);
            }
            int kc3 = ki2 * 4 + quad;
            int sw  = (kc3 ^ (l15 & 7)) << 3;        // uniform across f
            #pragma unroll
            for (int f = 0; f < 8; ++f) {
                f16x8 bb = *reinterpret_cast<const f16x8*>(
                    sb + (f * 16 + l15) * 64 + sw);
                #pragma unroll
                for (int tt = 0; tt < 4; ++tt)
                    acc[tt][f] = __builtin_amdgcn_mfma_f32_16x16x32_f16(A[tt], bb, acc[tt][f], 0, 0, 0);
            }
        }
    }

    #pragma unroll
    for (int tt = 0; tt < 4; ++tt) {
        float* o = out + (size_t)(b * 256 + t0 + tt) * 64 * 128;
        #pragma unroll
        for (int f = 0; f < 8; ++f) {
            int oc = f * 16 + l15;
            float bv = b2[oc];
            #pragma unroll
            for (int v = 0; v < 4; ++v) {
                int u = u0 + quad * 4 + v;
                o[u * 128 + oc] = acc[tt][f][v] + bv;
            }
        }
    }
}

// ---------------------------------------------------------------- launch
extern "C" void kernel_launch(void* const* d_in, const int* in_sizes, int n_in,
                              void* d_out, int out_size, void* d_ws, size_t ws_size,
                              hipStream_t stream) {
    const float* enc = (const float*)d_in[0]; // [8][256][512]
    const float* dec = (const float*)d_in[1]; // [8][64][512]
    const float* W1  = (const float*)d_in[2]; // [1024][1024]
    const float* b1  = (const float*)d_in[3]; // [1024]
    const float* W2  = (const float*)d_in[4]; // [1024][128]
    const float* b2  = (const float*)d_in[5]; // [128]
    float* out = (float*)d_out;

    char* ws = (char*)d_ws;
    _Float16* W1T = (_Float16*)(ws);                               // 2 MiB
    _Float16* W2T = (_Float16*)(ws + (2u << 20));                  // 256 KiB
    _Float16* EpP = (_Float16*)(ws + (2u << 20) + (256u << 10));   // 4 MiB
    _Float16* DpP = (_Float16*)(ws + (6u << 20) + (256u << 10));   // 1 MiB

    transpose_both<<<dim3(36, 32), dim3(32, 32), 0, stream>>>(W1, W2, W1T, W2T);

    // fused projections + exp2 epilogue: M = 2048 (enc) + 512 (dec)
    // v2: 16x32 per-wave tile -> 1280 blocks (5 waves/SIMD)
    proj_exp<<<dim3(32, 40), 256, 0, stream>>>(enc, dec, W1T, b1, EpP, DpP);

    joint_main<<<dim3(64, 8), 256, 0, stream>>>(EpP, DpP, W2T, b2, out);
}

// Round 4
// 138.432 us; speedup vs baseline: 1.1654x; 1.1478x over previous
//
#include <hip/hip_runtime.h>
#include <hip/hip_bf16.h>

// Joint network: out[b,t,u,o] = tanh(enc_proj[b,t,:] + dec_proj[b,u,:] + b1) @ W2 + b2
// B=8 T=256 U=64 D=512 H=1024 O=128.  All I/O fp32.
//
// tanh identity: with C2L = 2*log2(e),
//   tanh(x) = 1 - 2/(2^(C2L*x) + 1),  2^(C2L*(e+d+b1)) = Ep * Dp
// Ep/Dp precomputed fp16 in the projection epilogue. In the hot loop:
//   p = min(Ep*Dp + 1, 126)            (cap: err <= 0.016 where tanh ~ 1)
//   pairwise: rq = rcph(p0*p1); 1/p0 = p1*rq; 1/p1 = p0*rq   (4 rcph per 8)
//   A = 1 - 2*r
//
// ws: W1T f16 [1024][1024] @0 (2MiB) | W2T f16 [128][1024] @2MiB (256KiB)
//     Ep f16 [2048][1024] @2.25MiB (4MiB) | Dp f16 [512][1024] @6.25MiB (1MiB)

typedef _Float16 f16x8 __attribute__((ext_vector_type(8)));
typedef _Float16 f16x2 __attribute__((ext_vector_type(2)));
typedef float    f32x4 __attribute__((ext_vector_type(4)));

#define C2L 2.8853900817779268f

__device__ __forceinline__ float fast_exp2(float x) { return __builtin_amdgcn_exp2f(x); }

// v_cvt_pkrtz_f16_f32 returns __fp16x2 — bitcast to our _Float16x2
__device__ __forceinline__ f16x2 pk_cvt(float x, float y) {
    auto r = __builtin_amdgcn_cvt_pkrtz(x, y);
    union { decltype(r) a; f16x2 b; } c; c.a = r; return c.b;
}

// tanh on 8 packed f16 via pairwise reciprocal (4 rcph instead of 8).
// p = e*d + 1 in (1, inf); capped at 126 so q = p0*p1 <= 15876 keeps
// rq = rcph(q) >= 6.3e-5 in the f16 normal range (no denormal/overflow path).
__device__ __forceinline__ f16x8 tanh8(f16x8 e, f16x8 d) {
    const f16x8 one = {1,1,1,1,1,1,1,1};
    const f16x8 two = {2,2,2,2,2,2,2,2};
    const f16x8 cap = {126,126,126,126,126,126,126,126};
    union { f16x8 v; _Float16 s[8]; } p, r;
    p.v = e * d + one;                              // v_pk_fma_f16 x4
    p.v = __builtin_elementwise_min(p.v, cap);      // v_pk_min_f16 x4
    #pragma unroll
    for (int i = 0; i < 4; ++i) {
        _Float16 q  = p.s[2*i] * p.s[2*i+1];
        _Float16 rq = __builtin_amdgcn_rcph(q);
        r.s[2*i]   = p.s[2*i+1] * rq;               // = 1/p0
        r.s[2*i+1] = p.s[2*i]   * rq;               // = 1/p1
    }
    return one - two * r.v;                         // v_pk_fma_f16 x4
}

// async 16B global -> LDS (LDS dest is wave-uniform base + lane*16)
__device__ __forceinline__ void stage16(const void* g, void* l) {
    __builtin_amdgcn_global_load_lds(
        (const __attribute__((address_space(1))) unsigned int*)g,
        (__attribute__((address_space(3))) unsigned int*)l, 16, 0, 0);
}

// ---------------------------------------------------------------- transpose
// bx<32: W1 (1024x1024) -> W1T ; bx>=32: W2 (1024x128) -> W2T
// (R0 version — the 64x64/f16x8-store rewrite measured no better, R2.)
__global__ __launch_bounds__(1024) void transpose_both(
    const float* __restrict__ W1, const float* __restrict__ W2,
    _Float16* __restrict__ W1T, _Float16* __restrict__ W2T)
{
    __shared__ float tile[32][33];
    int bx = blockIdx.x;
    const float* src; _Float16* dst; int C, c0;
    if (bx < 32) { src = W1; dst = W1T; C = 1024; c0 = bx * 32; }
    else         { src = W2; dst = W2T; C = 128;  c0 = (bx - 32) * 32; }
    int r0 = blockIdx.y * 32;
    int tx = threadIdx.x, ty = threadIdx.y;
    tile[ty][tx] = src[(r0 + ty) * C + (c0 + tx)];
    __syncthreads();
    dst[(size_t)(c0 + ty) * 1024 + (r0 + tx)] = (_Float16)tile[tx][ty];
}

// ---------------------------------------------------------------- projections
// rows 0..2047 -> Ep = 2^(C2L*(enc@W1[:512] + b1)); rows 2048.. -> Dp (dec, no bias)
// v3: joint_main's proven structure. 64x64 tile per block (4 waves, wave w
// owns rows [16w,16w+16), 4 n-frags each). W1T panel staged to LDS via
// global_load_lds, double-buffered BK=64, one barrier per tile — stage(it+1)
// is in flight across the whole compute(it); the barrier's vmcnt drain covers
// loads issued a full tile earlier. Same XOR chunk swizzle as joint_main
// (measured 0 bank conflicts). A rows prefetched one full tile deep in
// registers (4 float4/lane). Removes all global latency from the MFMA chain
// — v1/v2 were latency-bound on cold A-loads + L2 B-loads with no lookahead.
__global__ __launch_bounds__(256, 2) void proj_exp(
    const float* __restrict__ enc,     // [2048][512]
    const float* __restrict__ dec,     // [512][512]
    const _Float16* __restrict__ W1T,  // [1024][1024]
    const float* __restrict__ b1,      // [1024]
    _Float16* __restrict__ Ep,         // [2048][1024]
    _Float16* __restrict__ Dp)         // [512][1024]
{
    __shared__ _Float16 sB[2][64 * 64];   // 2 x 8 KiB: [n-col][k] swizzled

    const int K = 512;
    int tid  = threadIdx.x;
    int w    = tid >> 6, lane = tid & 63;
    int quad = lane >> 4, l15 = lane & 15;
    int m_base = blockIdx.y * 64;
    int n_base = blockIdx.x * 64;

    bool is_enc = (m_base < 2048);          // block-uniform (boundary 2048 = 32*64)
    int row = m_base + w * 16 + l15;
    const float* A = is_enc ? (enc + (size_t)row * K)
                            : (dec + (size_t)(row - 2048) * K);
    const _Float16* Bsrc = W1T + (is_enc ? 0 : 512);

    f32x4 acc[4] = {};

    // stage B tile 0 (64 cols x 64 k f16 = 8 KiB): 512 chunks of 16B, 2/thread
    #pragma unroll
    for (int i = 0; i < 2; ++i) {
        int c = i * 256 + tid;
        int r = c >> 3, kcs = c & 7;
        stage16(Bsrc + (size_t)(n_base + r) * 1024 + ((kcs ^ (r & 7)) << 3),
                &sB[0][(i * 256 + (tid & 0xC0)) * 8]);
    }
    // A prefetch for tile 0: lane's 16 floats at k = quad*8 (+32)
    float4 a0lo = *reinterpret_cast<const float4*>(A + quad * 8);
    float4 a0hi = *reinterpret_cast<const float4*>(A + quad * 8 + 4);
    float4 a1lo = *reinterpret_cast<const float4*>(A + 32 + quad * 8);
    float4 a1hi = *reinterpret_cast<const float4*>(A + 32 + quad * 8 + 4);

    for (int it = 0; it < 8; ++it) {
        __syncthreads();   // drains stage(it) — issued one full tile ago
        float4 n0lo, n0hi, n1lo, n1hi;
        if (it < 7) {
            int kb = (it + 1) * 64;
            _Float16* dst = sB[(it + 1) & 1];
            #pragma unroll
            for (int i = 0; i < 2; ++i) {
                int c = i * 256 + tid;
                int r = c >> 3, kcs = c & 7;
                stage16(Bsrc + (size_t)(n_base + r) * 1024 + kb + ((kcs ^ (r & 7)) << 3),
                        dst + (i * 256 + (tid & 0xC0)) * 8);
            }
            n0lo = *reinterpret_cast<const float4*>(A + kb + quad * 8);
            n0hi = *reinterpret_cast<const float4*>(A + kb + quad * 8 + 4);
            n1lo = *reinterpret_cast<const float4*>(A + kb + 32 + quad * 8);
            n1hi = *reinterpret_cast<const float4*>(A + kb + 32 + quad * 8 + 4);
        }
        const _Float16* sb = sB[it & 1];
        // ki2 = 0
        {
            union { f16x8 v; f16x2 h[4]; } a;
            a.h[0] = pk_cvt(a0lo.x, a0lo.y);
            a.h[1] = pk_cvt(a0lo.z, a0lo.w);
            a.h[2] = pk_cvt(a0hi.x, a0hi.y);
            a.h[3] = pk_cvt(a0hi.z, a0hi.w);
            int sw = ((0 * 4 + quad) ^ (l15 & 7)) << 3;
            #pragma unroll
            for (int f = 0; f < 4; ++f) {
                f16x8 bb = *reinterpret_cast<const f16x8*>(sb + (f * 16 + l15) * 64 + sw);
                acc[f] = __builtin_amdgcn_mfma_f32_16x16x32_f16(a.v, bb, acc[f], 0, 0, 0);
            }
        }
        // ki2 = 1
        {
            union { f16x8 v; f16x2 h[4]; } a;
            a.h[0] = pk_cvt(a1lo.x, a1lo.y);
            a.h[1] = pk_cvt(a1lo.z, a1lo.w);
            a.h[2] = pk_cvt(a1hi.x, a1hi.y);
            a.h[3] = pk_cvt(a1hi.z, a1hi.w);
            int sw = ((1 * 4 + quad) ^ (l15 & 7)) << 3;
            #pragma unroll
            for (int f = 0; f < 4; ++f) {
                f16x8 bb = *reinterpret_cast<const f16x8*>(sb + (f * 16 + l15) * 64 + sw);
                acc[f] = __builtin_amdgcn_mfma_f32_16x16x32_f16(a.v, bb, acc[f], 0, 0, 0);
            }
        }
        a0lo = n0lo; a0hi = n0hi; a1lo = n1lo; a1hi = n1hi;
    }

    #pragma unroll
    for (int f = 0; f < 4; ++f) {
        int col = n_base + f * 16 + l15;
        float bv = is_enc ? b1[col] : 0.0f;
        #pragma unroll
        for (int v = 0; v < 4; ++v) {
            int orow = m_base + w * 16 + quad * 4 + v;
            float val = fast_exp2(C2L * (acc[f][v] + bv));
            if (is_enc) Ep[(size_t)orow * 1024 + col] = (_Float16)val;
            else        Dp[(size_t)(orow - 2048) * 1024 + col] = (_Float16)val;
        }
    }
}

// ---------------------------------------------------------------- main fused
// Block = (b, t-quad): 4 t x 64 u x 128 o. 4 waves; wave w owns u-rows
// [16w,16w+16) for all 4 t. Each W2T LDS fragment feeds 4 MFMAs.
// Ep rows (4 x 2 KiB) staged to LDS at block start; Dp stays as direct
// global loads (L2-resident, 128-way reused — staging it regressed, R2).
// W2T staged double-buffered (BK=64), one barrier per tile; XOR chunk
// swizzle keeps reads at 2-way bank aliasing with the lane-linear LDS dest
// required by global_load_lds.  (Exact R1 structure: best measured, 48-51 us.)
__global__ __launch_bounds__(256, 2) void joint_main(
    const _Float16* __restrict__ Ep,   // [2048][1024]
    const _Float16* __restrict__ Dp,   // [512][1024]
    const _Float16* __restrict__ W2T,  // [128][1024]
    const float* __restrict__ b2,      // [128]
    float* __restrict__ out)           // [8][256][64][128]
{
    __shared__ _Float16 sB[2][128 * 64];   // 2 x 16 KiB
    __shared__ _Float16 sE[4 * 1024];      // 8 KiB: 4 Ep rows

    int t0 = blockIdx.x * 4, b = blockIdx.y;
    int tid  = threadIdx.x;
    int w    = tid >> 6, lane = tid & 63;
    int quad = lane >> 4, l15 = lane & 15;
    int u0   = w * 16;

    const _Float16* epB = Ep + (size_t)(b * 256 + t0) * 1024;   // 4 contiguous rows
    const _Float16* dpr = Dp + (size_t)(b * 64 + u0 + l15) * 1024;

    f32x4 acc[4][8] = {};   // [t][o-tile] = 128 AGPRs

    // stage 4 Ep rows (8 KiB, linear both sides): 512 chunks, 2 per thread
    #pragma unroll
    for (int i = 0; i < 2; ++i) {
        int c = i * 256 + tid;
        stage16(epB + c * 8, sE + (i * 256 + (tid & 0xC0)) * 8);
    }
    // stage W2T tile 0 into buf 0 (1024 chunks of 16B, 4 per thread)
    #pragma unroll
    for (int i = 0; i < 4; ++i) {
        int c = i * 256 + tid;
        int row = c >> 3, kcs = c & 7;
        stage16(W2T + row * 1024 + ((kcs ^ (row & 7)) << 3),
                &sB[0][(i * 256 + (tid & 0xC0)) * 8]);
    }

    for (int it = 0; it < 16; ++it) {
        __syncthreads();   // drains stage(it) — issued one full tile ago (and sE at it=0)
        if (it < 15) {
            int kb = (it + 1) * 64;
            _Float16* dst = sB[(it + 1) & 1];
            #pragma unroll
            for (int i = 0; i < 4; ++i) {
                int c = i * 256 + tid;
                int row = c >> 3, kcs = c & 7;
                stage16(W2T + row * 1024 + kb + ((kcs ^ (row & 7)) << 3),
                        dst + (i * 256 + (tid & 0xC0)) * 8);
            }
        }
        const _Float16* sb = sB[it & 1];
        #pragma unroll
        for (int ki2 = 0; ki2 < 2; ++ki2) {
            int k = it * 64 + ki2 * 32 + quad * 8;
            f16x8 d8 = *reinterpret_cast<const f16x8*>(dpr + k);
            f16x8 A[4];
            #pragma unroll
            for (int tt = 0; tt < 4; ++tt) {
                // broadcast ds_read_b128 (same addr per quad group): conflict-free
                f16x8 e = *reinterpret_cast<const f16x8*>(sE + tt * 1024 + k);
                A[tt] = tanh8(e, d8);
            }
            int kc3 = ki2 * 4 + quad;
            int sw  = (kc3 ^ (l15 & 7)) << 3;        // uniform across f
            #pragma unroll
            for (int f = 0; f < 8; ++f) {
                f16x8 bb = *reinterpret_cast<const f16x8*>(
                    sb + (f * 16 + l15) * 64 + sw);
                #pragma unroll
                for (int tt = 0; tt < 4; ++tt)
                    acc[tt][f] = __builtin_amdgcn_mfma_f32_16x16x32_f16(A[tt], bb, acc[tt][f], 0, 0, 0);
            }
        }
    }

    #pragma unroll
    for (int tt = 0; tt < 4; ++tt) {
        float* o = out + (size_t)(b * 256 + t0 + tt) * 64 * 128;
        #pragma unroll
        for (int f = 0; f < 8; ++f) {
            int oc = f * 16 + l15;
            float bv = b2[oc];
            #pragma unroll
            for (int v = 0; v < 4; ++v) {
                int u = u0 + quad * 4 + v;
                o[u * 128 + oc] = acc[tt][f][v] + bv;
            }
        }
    }
}

// ---------------------------------------------------------------- launch
extern "C" void kernel_launch(void* const* d_in, const int* in_sizes, int n_in,
                              void* d_out, int out_size, void* d_ws, size_t ws_size,
                              hipStream_t stream) {
    const float* enc = (const float*)d_in[0]; // [8][256][512]
    const float* dec = (const float*)d_in[1]; // [8][64][512]
    const float* W1  = (const float*)d_in[2]; // [1024][1024]
    const float* b1  = (const float*)d_in[3]; // [1024]
    const float* W2  = (const float*)d_in[4]; // [1024][128]
    const float* b2  = (const float*)d_in[5]; // [128]
    float* out = (float*)d_out;

    char* ws = (char*)d_ws;
    _Float16* W1T = (_Float16*)(ws);                               // 2 MiB
    _Float16* W2T = (_Float16*)(ws + (2u << 20));                  // 256 KiB
    _Float16* EpP = (_Float16*)(ws + (2u << 20) + (256u << 10));   // 4 MiB
    _Float16* DpP = (_Float16*)(ws + (6u << 20) + (256u << 10));   // 1 MiB

    transpose_both<<<dim3(36, 32), dim3(32, 32), 0, stream>>>(W1, W2, W1T, W2T);

    // fused projections + exp2 epilogue: M = 2048 (enc) + 512 (dec)
    // v3: 64x64 tiles, LDS-staged B, double-buffered, A reg-prefetch
    proj_exp<<<dim3(16, 40), 256, 0, stream>>>(enc, dec, W1T, b1, EpP, DpP);

    joint_main<<<dim3(64, 8), 256, 0, stream>>>(EpP, DpP, W2T, b2, out);
}